// Round 2
// baseline (254.151 us; speedup 1.0000x reference)
//
#include <hip/hip_runtime.h>
#include <hip/hip_bf16.h>

#define NB 16
#define NP 1024
#define NS 32
#define NC 76
#define HSTR 136   // bf16 elems per col (k-dim stride); 272B/col

typedef __attribute__((ext_vector_type(8))) short bf16x8;
typedef __attribute__((ext_vector_type(4))) short bf16x4;
typedef __attribute__((ext_vector_type(2))) short bf16x2;
typedef __attribute__((ext_vector_type(4))) float f32x4;

__device__ inline short f2bf(float f) {
  unsigned u = __builtin_bit_cast(unsigned, f);
  u = u + 0x7fffu + ((u >> 16) & 1u);   // round-to-nearest-even
  return (short)(u >> 16);
}

// XOR swizzle: fold col bits 5..6 (the p-within-tile bits, bank-dead at any
// stride since 32*HSTR = 0 mod 32 words) into element bits 3..4 (16B units,
// so b128 reads stay contiguous). Per 16-col fragment window the XOR is
// uniform -> read-side bank pattern unchanged.
__device__ inline int swz(int col, int k) {
  return (col * HSTR + k) ^ ((((col) >> 5) & 3) << 3);
}

// ---------------- kernel 1: per-(b,p) frames ----------------
__global__ void frames_kernel(const float* __restrict__ inp,
                              const float* __restrict__ normal,
                              float* __restrict__ out, float* __restrict__ ws) {
  const int bp = blockIdx.x * 256 + threadIdx.x;   // 0..16383
  const int b = bp >> 10, p = bp & 1023;

  float azi[3];
#pragma unroll
  for (int i = 0; i < 3; ++i) {
    const float* row = inp + (size_t)((b*NC + 6 + i)*NP + p) * NS;
    float s = 0.f;
#pragma unroll
    for (int q = 0; q < 8; ++q) {
      float4 v = ((const float4*)row)[q];
      s += (v.x + v.y) + (v.z + v.w);
    }
    s -= row[0];                  // mean over s=1..31
    azi[i] = s / 31.f;
  }
  float nr[3];
#pragma unroll
  for (int i = 0; i < 3; ++i) nr[i] = normal[(size_t)(b*NP + p)*3 + i];
  float nn = sqrtf(nr[0]*nr[0] + nr[1]*nr[1] + nr[2]*nr[2]) + 1e-8f;
  nr[0] /= nn; nr[1] /= nn; nr[2] /= nn;
  float au[3] = {azi[0], azi[1], azi[2]};
  float an = sqrtf(au[0]*au[0] + au[1]*au[1] + au[2]*au[2]) + 1e-8f;
  au[0] /= an; au[1] /= an; au[2] /= an;
  float d = au[0]*nr[0] + au[1]*nr[1] + au[2]*nr[2];
  float xax[3] = {au[0] - d*nr[0], au[1] - d*nr[1], au[2] - d*nr[2]};
  float xn = sqrtf(xax[0]*xax[0] + xax[1]*xax[1] + xax[2]*xax[2]) + 1e-8f;
  xax[0] /= xn; xax[1] /= xn; xax[2] /= xn;
  float yax[3] = {nr[1]*xax[2] - nr[2]*xax[1],
                  nr[2]*xax[0] - nr[0]*xax[2],
                  nr[0]*xax[1] - nr[1]*xax[0]};
#pragma unroll
  for (int i = 0; i < 3; ++i)
    out[(size_t)(b*131 + i)*NP + p] = au[i];      // azi_u -> out channels 0..2

  float* w = ws + (size_t)bp * 12;                // R rows (xax,yax,n) + R*azi_u
  w[0]=xax[0]; w[1]=xax[1]; w[2]=xax[2];
  w[3]=yax[0]; w[4]=yax[1]; w[5]=yax[2];
  w[6]=nr[0];  w[7]=nr[1];  w[8]=nr[2];
  w[9]  = xax[0]*au[0] + xax[1]*au[1] + xax[2]*au[2];
  w[10] = yax[0]*au[0] + yax[1]*au[1] + yax[2]*au[2];
  w[11] = nr[0]*au[0]  + nr[1]*au[1]  + nr[2]*au[2];
}

// ---------------- kernel 2: fused MLP + pool (1 tile of 4 points / block) ----
// x in LDS, col-major [col=(lp,s)][k], swizzled:
//   k 0..63  = feats (input ch 12..75)
//   k 64..66 = align(rel), 67..69 = align(other_normal), 70..72 = dir_dif
//   k 73..95 = zero (w1 fragments also zero there)
__global__ __launch_bounds__(256, 4)
void mlp_kernel(const float* __restrict__ inp, const float* __restrict__ w1g,
                const float* __restrict__ b1g, const float* __restrict__ w2g,
                const float* __restrict__ b2g, const float* __restrict__ ws,
                float* __restrict__ out) {
  __shared__ short xh[128 * HSTR];   // 34.8 KB union: x tile, then h1 tile
  const int tid = threadIdx.x;
  const int lane = tid & 63;
  const int wv = tid >> 6;          // wave 0..3 -> output-row stripe 32*wv
  const int l15 = lane & 15;
  const int l4 = lane >> 4;         // 0..3

  const int tile = blockIdx.x;      // 0..4095
  const int b = tile >> 8;
  const int pbase = (tile & 255) * 4;

  // ----- per-wave weight fragments in registers -----
  bf16x8 w1f[2][3];
#pragma unroll
  for (int mf = 0; mf < 2; ++mf)
#pragma unroll
    for (int ks = 0; ks < 3; ++ks) {
      bf16x8 a;
#pragma unroll
      for (int j = 0; j < 8; ++j) {
        int row = 32*wv + 16*mf + l15;
        int kk = 32*ks + 8*l4 + j;
        float v = 0.f;
        if (kk < 73) {
          int c = (kk < 64) ? (kk + 3) : ((kk < 67) ? (kk - 64) : kk);
          v = w1g[row*73 + c];
        }
        a[j] = f2bf(v);
      }
      w1f[mf][ks] = a;
    }
  bf16x8 w2f[2][4];
#pragma unroll
  for (int mf = 0; mf < 2; ++mf)
#pragma unroll
    for (int ks = 0; ks < 4; ++ks) {
      bf16x8 a;
#pragma unroll
      for (int j = 0; j < 8; ++j) {
        int row = 32*wv + 16*mf + l15;
        int kk = 32*ks + 8*l4 + j;
        a[j] = f2bf(w2g[row*128 + kk]);
      }
      w2f[mf][ks] = a;
    }
  float bias1[2][4], bias2[2][4];
#pragma unroll
  for (int mf = 0; mf < 2; ++mf)
#pragma unroll
    for (int r = 0; r < 4; ++r) {
      int row = 32*wv + 16*mf + 4*l4 + r;
      bias1[mf][r] = b1g[row];
      bias2[mf][r] = b2g[row];
    }

  // ----- zero pad region k in [73,96) (guards vs NaN garbage on MFMA pad) ----
  for (int i = tid; i < 128*23; i += 256) {
    int col = i / 23;
    int k = 73 + (i - col*23);
    xh[swz(col, k)] = 0;
  }

  // ----- fill x tile: feats (k=0..63), float4 global loads + b64 LDS writes --
  {
    const int s4 = tid & 7;          // s quad
    const int lp = (tid >> 3) & 3;   // point within tile
    const int cql = tid >> 5;        // chq low (0..7)
    const int colb = lp*32 + 4*s4;
#pragma unroll
    for (int i = 0; i < 2; ++i) {
      const int chq = i*8 + cql;     // channel quad 0..15 -> k = 4*chq
      const float* base = inp + ((size_t)((b*NC + 12 + 4*chq)*NP) + pbase + lp)*NS + 4*s4;
      float4 v0 = *(const float4*)(base + 0*(size_t)NP*NS);
      float4 v1 = *(const float4*)(base + 1*(size_t)NP*NS);
      float4 v2 = *(const float4*)(base + 2*(size_t)NP*NS);
      float4 v3 = *(const float4*)(base + 3*(size_t)NP*NS);
      const float* f0 = (const float*)&v0;
      const float* f1 = (const float*)&v1;
      const float* f2 = (const float*)&v2;
      const float* f3 = (const float*)&v3;
#pragma unroll
      for (int j = 0; j < 4; ++j) {
        bf16x4 pk;
        pk[0] = f2bf(f0[j]); pk[1] = f2bf(f1[j]);
        pk[2] = f2bf(f2[j]); pk[3] = f2bf(f3[j]);
        *(bf16x4*)&xh[swz(colb + j, 4*chq)] = pk;
      }
    }
  }
  // ----- fill x tile: aligned rows (k=64..72) -----
  if (tid < 128) {
    const int col = tid;
    const int lp = col >> 5, s = col & 31;
    const int p = pbase + lp;
    const float* Rp = ws + (size_t)(b*NP + p)*12;
    float R[12];
#pragma unroll
    for (int i = 0; i < 12; ++i) R[i] = Rp[i];
    float rel[3], on[3], od[3];
#pragma unroll
    for (int i = 0; i < 3; ++i) {
      rel[i] = inp[(size_t)((b*NC + 6 + i)*NP + p)*NS + s];
      on[i]  = inp[(size_t)((b*NC + 3 + i)*NP + p)*NS + s];
      od[i]  = inp[(size_t)((b*NC + 9 + i)*NP + p)*NS + s];
    }
    float xv[9];
#pragma unroll
    for (int r = 0; r < 3; ++r) {
      xv[r]   = R[3*r]*rel[0] + R[3*r+1]*rel[1] + R[3*r+2]*rel[2];
      xv[3+r] = R[3*r]*on[0]  + R[3*r+1]*on[1]  + R[3*r+2]*on[2];
      xv[6+r] = R[9+r] - (R[3*r]*od[0] + R[3*r+1]*od[1] + R[3*r+2]*od[2]);
    }
#pragma unroll
    for (int q = 0; q < 4; ++q) {
      bf16x2 pk2; pk2[0] = f2bf(xv[2*q]); pk2[1] = f2bf(xv[2*q+1]);
      *(bf16x2*)&xh[swz(col, 64 + 2*q)] = pk2;
    }
    xh[swz(col, 72)] = f2bf(xv[8]);
  }
  __syncthreads();

  // ----- layer 1: h1 = relu(w1 @ x + b1), K=96 (padded) -----
  f32x4 acc1[2][8];
#pragma unroll
  for (int mf = 0; mf < 2; ++mf)
#pragma unroll
    for (int nf = 0; nf < 8; ++nf) acc1[mf][nf] = f32x4{0.f,0.f,0.f,0.f};
#pragma unroll
  for (int ks = 0; ks < 3; ++ks) {
    bf16x8 bv[8];
#pragma unroll
    for (int nf = 0; nf < 8; ++nf)
      bv[nf] = *(const bf16x8*)&xh[swz(16*nf + l15, 32*ks + 8*l4)];
#pragma unroll
    for (int mf = 0; mf < 2; ++mf)
#pragma unroll
      for (int nf = 0; nf < 8; ++nf)
        acc1[mf][nf] = __builtin_amdgcn_mfma_f32_16x16x32_bf16(
            w1f[mf][ks], bv[nf], acc1[mf][nf], 0, 0, 0);
  }
  __syncthreads();   // all L1 reads done before h1 overwrites xh

  // store h1 col-major [col][k=row] for layer-2 B fragments
#pragma unroll
  for (int mf = 0; mf < 2; ++mf)
#pragma unroll
    for (int nf = 0; nf < 8; ++nf) {
      const int col = 16*nf + l15;
      const int row0 = 32*wv + 16*mf + 4*l4;
      bf16x4 pk;
#pragma unroll
      for (int r = 0; r < 4; ++r)
        pk[r] = f2bf(fmaxf(acc1[mf][nf][r] + bias1[mf][r], 0.f));
      *(bf16x4*)&xh[swz(col, row0)] = pk;
    }
  __syncthreads();

  // ----- layer 2: h2 = relu(w2 @ h1 + b2), K=128 -----
  f32x4 acc2[2][8];
#pragma unroll
  for (int mf = 0; mf < 2; ++mf)
#pragma unroll
    for (int nf = 0; nf < 8; ++nf) acc2[mf][nf] = f32x4{0.f,0.f,0.f,0.f};
#pragma unroll
  for (int ks = 0; ks < 4; ++ks) {
    bf16x8 bv[8];
#pragma unroll
    for (int nf = 0; nf < 8; ++nf)
      bv[nf] = *(const bf16x8*)&xh[swz(16*nf + l15, 32*ks + 8*l4)];
#pragma unroll
    for (int mf = 0; mf < 2; ++mf)
#pragma unroll
      for (int nf = 0; nf < 8; ++nf)
        acc2[mf][nf] = __builtin_amdgcn_mfma_f32_16x16x32_bf16(
            w2f[mf][ks], bv[nf], acc2[mf][nf], 0, 0, 0);
  }

  // ----- relu + max-pool over s (16-lane shuffle reduce) + store -----
#pragma unroll
  for (int mf = 0; mf < 2; ++mf)
#pragma unroll
    for (int r = 0; r < 4; ++r)
#pragma unroll
      for (int lp = 0; lp < 4; ++lp) {
        float v = fmaxf(fmaxf(acc2[mf][2*lp][r], acc2[mf][2*lp+1][r]) + bias2[mf][r], 0.f);
#pragma unroll
        for (int off = 1; off < 16; off <<= 1)
          v = fmaxf(v, __shfl_xor(v, off));
        if (l15 == lp) {
          const int row = 32*wv + 16*mf + 4*l4 + r;
          out[(size_t)(b*131 + 3 + row)*NP + pbase + lp] = v;
        }
      }
}

extern "C" void kernel_launch(void* const* d_in, const int* in_sizes, int n_in,
                              void* d_out, int out_size, void* d_ws, size_t ws_size,
                              hipStream_t stream) {
  const float* inp    = (const float*)d_in[0];
  const float* normal = (const float*)d_in[1];
  const float* w1     = (const float*)d_in[2];
  const float* b1     = (const float*)d_in[3];
  const float* w2     = (const float*)d_in[4];
  const float* b2     = (const float*)d_in[5];
  float* out = (float*)d_out;
  float* ws  = (float*)d_ws;    // needs 16384*12*4 = 786,432 B

  frames_kernel<<<dim3((NB*NP)/256), dim3(256), 0, stream>>>(inp, normal, out, ws);
  mlp_kernel<<<dim3(NB*NP/4), dim3(256), 0, stream>>>(inp, w1, b1, w2, b2, ws, out);
}

// Round 3
// 131.307 us; speedup vs baseline: 1.9356x; 1.9356x over previous
//
#include <hip/hip_runtime.h>
#include <hip/hip_bf16.h>

#define NB 16
#define NP 1024
#define NS 32
#define NC 76
#define HSTR 136   // bf16 elems per col (k-dim stride); 272B/col
#define TPB 2      // tiles (of 4 points / 128 cols) per block

typedef __attribute__((ext_vector_type(8))) short bf16x8;
typedef __attribute__((ext_vector_type(4))) short bf16x4;
typedef __attribute__((ext_vector_type(2))) short bf16x2;
typedef __attribute__((ext_vector_type(4))) float f32x4;

__device__ inline short f2bf(float f) {
  unsigned u = __builtin_bit_cast(unsigned, f);
  u = u + 0x7fffu + ((u >> 16) & 1u);   // round-to-nearest-even
  return (short)(u >> 16);
}

// XOR swizzle: fold col bits 5..6 (bank-dead at stride 32*HSTR) into element
// bits 3..4 (16B units, so b128 reads stay contiguous). Uniform per 16-col
// fragment window -> read-side bank pattern unchanged.
__device__ inline int swz(int col, int k) {
  return (col * HSTR + k) ^ ((((col) >> 5) & 3) << 3);
}

// ---------------- kernel 1: per-(b,p) frames ----------------
__global__ void frames_kernel(const float* __restrict__ inp,
                              const float* __restrict__ normal,
                              float* __restrict__ out, float* __restrict__ ws) {
  const int bp = blockIdx.x * 256 + threadIdx.x;   // 0..16383
  const int b = bp >> 10, p = bp & 1023;

  float azi[3];
#pragma unroll
  for (int i = 0; i < 3; ++i) {
    const float* row = inp + (size_t)((b*NC + 6 + i)*NP + p) * NS;
    float s = 0.f;
#pragma unroll
    for (int q = 0; q < 8; ++q) {
      float4 v = ((const float4*)row)[q];
      s += (v.x + v.y) + (v.z + v.w);
    }
    s -= row[0];                  // mean over s=1..31
    azi[i] = s / 31.f;
  }
  float nr[3];
#pragma unroll
  for (int i = 0; i < 3; ++i) nr[i] = normal[(size_t)(b*NP + p)*3 + i];
  float nn = sqrtf(nr[0]*nr[0] + nr[1]*nr[1] + nr[2]*nr[2]) + 1e-8f;
  nr[0] /= nn; nr[1] /= nn; nr[2] /= nn;
  float au[3] = {azi[0], azi[1], azi[2]};
  float an = sqrtf(au[0]*au[0] + au[1]*au[1] + au[2]*au[2]) + 1e-8f;
  au[0] /= an; au[1] /= an; au[2] /= an;
  float d = au[0]*nr[0] + au[1]*nr[1] + au[2]*nr[2];
  float xax[3] = {au[0] - d*nr[0], au[1] - d*nr[1], au[2] - d*nr[2]};
  float xn = sqrtf(xax[0]*xax[0] + xax[1]*xax[1] + xax[2]*xax[2]) + 1e-8f;
  xax[0] /= xn; xax[1] /= xn; xax[2] /= xn;
  float yax[3] = {nr[1]*xax[2] - nr[2]*xax[1],
                  nr[2]*xax[0] - nr[0]*xax[2],
                  nr[0]*xax[1] - nr[1]*xax[0]};
#pragma unroll
  for (int i = 0; i < 3; ++i)
    out[(size_t)(b*131 + i)*NP + p] = au[i];      // azi_u -> out channels 0..2

  float* w = ws + (size_t)bp * 12;                // R rows (xax,yax,n) + R*azi_u
  w[0]=xax[0]; w[1]=xax[1]; w[2]=xax[2];
  w[3]=yax[0]; w[4]=yax[1]; w[5]=yax[2];
  w[6]=nr[0];  w[7]=nr[1];  w[8]=nr[2];
  w[9]  = xax[0]*au[0] + xax[1]*au[1] + xax[2]*au[2];
  w[10] = yax[0]*au[0] + yax[1]*au[1] + yax[2]*au[2];
  w[11] = nr[0]*au[0]  + nr[1]*au[1]  + nr[2]*au[2];
}

// ---------------- kernel 2: fused MLP + pool ----------------
// 512 threads = 8 waves; wave wv owns output rows 16*wv .. 16*wv+15.
// x in LDS, col-major [col=(lp,s)][k], swizzled:
//   k 0..63  = feats (input ch 12..75)
//   k 64..66 = align(rel), 67..69 = align(other_normal), 70..72 = dir_dif
//   k 73..95 = zero (w1 fragments also zero there)
__global__ __launch_bounds__(512, 2)
void mlp_kernel(const float* __restrict__ inp, const float* __restrict__ w1g,
                const float* __restrict__ b1g, const float* __restrict__ w2g,
                const float* __restrict__ b2g, const float* __restrict__ ws,
                float* __restrict__ out) {
  __shared__ short xh[128 * HSTR];   // 34.8 KB union: x tile, then h1 tile
  const int tid = threadIdx.x;
  const int lane = tid & 63;
  const int wv = tid >> 6;          // wave 0..7 -> output-row stripe 16*wv
  const int l15 = lane & 15;
  const int l4 = lane >> 4;         // 0..3

  // ----- per-wave weight fragments in registers (one 16-row stripe) -----
  bf16x8 w1f[3];
#pragma unroll
  for (int ks = 0; ks < 3; ++ks) {
    bf16x8 a;
#pragma unroll
    for (int j = 0; j < 8; ++j) {
      int row = 16*wv + l15;
      int kk = 32*ks + 8*l4 + j;
      float v = 0.f;
      if (kk < 73) {
        int c = (kk < 64) ? (kk + 3) : ((kk < 67) ? (kk - 64) : kk);
        v = w1g[row*73 + c];
      }
      a[j] = f2bf(v);
    }
    w1f[ks] = a;
  }
  bf16x8 w2f[4];
#pragma unroll
  for (int ks = 0; ks < 4; ++ks) {
    bf16x8 a;
#pragma unroll
    for (int j = 0; j < 8; ++j) {
      int row = 16*wv + l15;
      int kk = 32*ks + 8*l4 + j;
      a[j] = f2bf(w2g[row*128 + kk]);
    }
    w2f[ks] = a;
  }
  float bias1[4], bias2[4];
#pragma unroll
  for (int r = 0; r < 4; ++r) {
    int row = 16*wv + 4*l4 + r;
    bias1[r] = b1g[row];
    bias2[r] = b2g[row];
  }

  // zero the pad region k in [73,96) once (tile 0 guard; later tiles hold
  // finite h1 leftovers there, annihilated by the zero w1 fragments)
  for (int i = tid; i < 128*23; i += 512) {
    int col = i / 23;
    int k = 73 + (i - col*23);
    xh[swz(col, k)] = 0;
  }

  for (int it = 0; it < TPB; ++it) {
    const int tile = blockIdx.x * TPB + it;       // 0..4095
    const int b = tile >> 8;
    const int pbase = (tile & 255) * 4;

    // ----- fill feats (k=0..63): 4 float4 loads/thread, transpose, b64 writes
    {
      const int s4 = tid & 7;          // s quad: s = 4*s4..4*s4+3
      const int lp = (tid >> 3) & 3;   // point within tile
      const int chq = tid >> 5;        // channel quad 0..15 -> k = 4*chq
      const int colb = lp*32 + 4*s4;
      const float* base = inp + ((size_t)((b*NC + 12 + 4*chq)*NP) + pbase + lp)*NS + 4*s4;
      float4 v0 = *(const float4*)(base + 0*(size_t)NP*NS);
      float4 v1 = *(const float4*)(base + 1*(size_t)NP*NS);
      float4 v2 = *(const float4*)(base + 2*(size_t)NP*NS);
      float4 v3 = *(const float4*)(base + 3*(size_t)NP*NS);
      const float* f0 = (const float*)&v0;
      const float* f1 = (const float*)&v1;
      const float* f2 = (const float*)&v2;
      const float* f3 = (const float*)&v3;
#pragma unroll
      for (int j = 0; j < 4; ++j) {
        bf16x4 pk;
        pk[0] = f2bf(f0[j]); pk[1] = f2bf(f1[j]);
        pk[2] = f2bf(f2[j]); pk[3] = f2bf(f3[j]);
        *(bf16x4*)&xh[swz(colb + j, 4*chq)] = pk;
      }
    }
    // ----- fill aligned rows (k=64..72) -----
    if (tid < 128) {
      const int col = tid;
      const int lp = col >> 5, s = col & 31;
      const int p = pbase + lp;
      const float* Rp = ws + (size_t)(b*NP + p)*12;
      float R[12];
#pragma unroll
      for (int i = 0; i < 12; ++i) R[i] = Rp[i];
      float rel[3], on[3], od[3];
#pragma unroll
      for (int i = 0; i < 3; ++i) {
        rel[i] = inp[(size_t)((b*NC + 6 + i)*NP + p)*NS + s];
        on[i]  = inp[(size_t)((b*NC + 3 + i)*NP + p)*NS + s];
        od[i]  = inp[(size_t)((b*NC + 9 + i)*NP + p)*NS + s];
      }
      float xv[9];
#pragma unroll
      for (int r = 0; r < 3; ++r) {
        xv[r]   = R[3*r]*rel[0] + R[3*r+1]*rel[1] + R[3*r+2]*rel[2];
        xv[3+r] = R[3*r]*on[0]  + R[3*r+1]*on[1]  + R[3*r+2]*on[2];
        xv[6+r] = R[9+r] - (R[3*r]*od[0] + R[3*r+1]*od[1] + R[3*r+2]*od[2]);
      }
#pragma unroll
      for (int q = 0; q < 4; ++q) {
        bf16x2 pk2; pk2[0] = f2bf(xv[2*q]); pk2[1] = f2bf(xv[2*q+1]);
        *(bf16x2*)&xh[swz(col, 64 + 2*q)] = pk2;
      }
      xh[swz(col, 72)] = f2bf(xv[8]);
    }
    __syncthreads();

    // ----- layer 1: h1 = relu(w1 @ x + b1), K=96 (padded) -----
    f32x4 acc1[8];
#pragma unroll
    for (int nf = 0; nf < 8; ++nf) acc1[nf] = f32x4{0.f,0.f,0.f,0.f};
#pragma unroll
    for (int ks = 0; ks < 3; ++ks) {
      bf16x8 bv[8];
#pragma unroll
      for (int nf = 0; nf < 8; ++nf)
        bv[nf] = *(const bf16x8*)&xh[swz(16*nf + l15, 32*ks + 8*l4)];
#pragma unroll
      for (int nf = 0; nf < 8; ++nf)
        acc1[nf] = __builtin_amdgcn_mfma_f32_16x16x32_bf16(
            w1f[ks], bv[nf], acc1[nf], 0, 0, 0);
    }
    __syncthreads();   // all L1 reads done before h1 overwrites xh

    // store h1 col-major [col][k=row] for layer-2 B fragments
#pragma unroll
    for (int nf = 0; nf < 8; ++nf) {
      const int col = 16*nf + l15;
      const int row0 = 16*wv + 4*l4;
      bf16x4 pk;
#pragma unroll
      for (int r = 0; r < 4; ++r)
        pk[r] = f2bf(fmaxf(acc1[nf][r] + bias1[r], 0.f));
      *(bf16x4*)&xh[swz(col, row0)] = pk;
    }
    __syncthreads();

    // ----- layer 2: h2 = relu(w2 @ h1 + b2), K=128 -----
    f32x4 acc2[8];
#pragma unroll
    for (int nf = 0; nf < 8; ++nf) acc2[nf] = f32x4{0.f,0.f,0.f,0.f};
#pragma unroll
    for (int ks = 0; ks < 4; ++ks) {
      bf16x8 bv[8];
#pragma unroll
      for (int nf = 0; nf < 8; ++nf)
        bv[nf] = *(const bf16x8*)&xh[swz(16*nf + l15, 32*ks + 8*l4)];
#pragma unroll
      for (int nf = 0; nf < 8; ++nf)
        acc2[nf] = __builtin_amdgcn_mfma_f32_16x16x32_bf16(
            w2f[ks], bv[nf], acc2[nf], 0, 0, 0);
    }

    // ----- relu + max-pool over s (16-lane shuffle reduce) + store -----
#pragma unroll
    for (int r = 0; r < 4; ++r)
#pragma unroll
      for (int lp = 0; lp < 4; ++lp) {
        float v = fmaxf(fmaxf(acc2[2*lp][r], acc2[2*lp+1][r]) + bias2[r], 0.f);
#pragma unroll
        for (int off = 1; off < 16; off <<= 1)
          v = fmaxf(v, __shfl_xor(v, off));
        if (l15 == lp) {
          const int row = 16*wv + 4*l4 + r;
          out[(size_t)(b*131 + 3 + row)*NP + pbase + lp] = v;
        }
      }
    __syncthreads();   // xh reads complete before next tile's fill
  }
}

extern "C" void kernel_launch(void* const* d_in, const int* in_sizes, int n_in,
                              void* d_out, int out_size, void* d_ws, size_t ws_size,
                              hipStream_t stream) {
  const float* inp    = (const float*)d_in[0];
  const float* normal = (const float*)d_in[1];
  const float* w1     = (const float*)d_in[2];
  const float* b1     = (const float*)d_in[3];
  const float* w2     = (const float*)d_in[4];
  const float* b2     = (const float*)d_in[5];
  float* out = (float*)d_out;
  float* ws  = (float*)d_ws;    // needs 16384*12*4 = 786,432 B

  frames_kernel<<<dim3((NB*NP)/256), dim3(256), 0, stream>>>(inp, normal, out, ws);
  mlp_kernel<<<dim3(NB*NP/4/TPB), dim3(512), 0, stream>>>(inp, w1, b1, w2, b2, ws, out);
}

// Round 4
// 93.773 us; speedup vs baseline: 2.7103x; 1.4003x over previous
//
#include <hip/hip_runtime.h>
#include <hip/hip_bf16.h>

#define NB 16
#define NP 1024
#define NS 32
#define NC 76
#define HSTR 136   // bf16 elems per col (k-dim stride); 272B/col
#define TPB 4      // tiles (of 4 points / 128 cols) per block

typedef __attribute__((ext_vector_type(8))) short bf16x8;
typedef __attribute__((ext_vector_type(4))) short bf16x4;
typedef __attribute__((ext_vector_type(2))) short bf16x2;
typedef __attribute__((ext_vector_type(4))) float f32x4;

__device__ inline short f2bf(float f) {
  unsigned u = __builtin_bit_cast(unsigned, f);
  u = u + 0x7fffu + ((u >> 16) & 1u);   // round-to-nearest-even
  return (short)(u >> 16);
}

// XOR swizzle: fold col bits 5..6 (bank-dead at stride 32*HSTR) into element
// bits 3..4 (16B units, so b128 reads stay contiguous). Uniform per 16-col
// fragment window -> read-side bank pattern unchanged.
__device__ inline int swz(int col, int k) {
  return (col * HSTR + k) ^ ((((col) >> 5) & 3) << 3);
}

// max over the 16-lane row (l15 dimension) via DPP butterfly — no LDS traffic
__device__ inline float dpp_max16(float v) {
  int x;
  x = __builtin_amdgcn_update_dpp(0, __builtin_bit_cast(int, v), 0xB1, 0xf, 0xf, true);   // quad_perm(1,0,3,2): xor1
  v = fmaxf(v, __builtin_bit_cast(float, x));
  x = __builtin_amdgcn_update_dpp(0, __builtin_bit_cast(int, v), 0x4E, 0xf, 0xf, true);   // quad_perm(2,3,0,1): xor2
  v = fmaxf(v, __builtin_bit_cast(float, x));
  x = __builtin_amdgcn_update_dpp(0, __builtin_bit_cast(int, v), 0x141, 0xf, 0xf, true);  // row_half_mirror: xor4-equiv
  v = fmaxf(v, __builtin_bit_cast(float, x));
  x = __builtin_amdgcn_update_dpp(0, __builtin_bit_cast(int, v), 0x140, 0xf, 0xf, true);  // row_mirror: xor8-equiv
  v = fmaxf(v, __builtin_bit_cast(float, x));
  return v;
}

// ---------------- kernel 1: per-(b,p) frames ----------------
__global__ void frames_kernel(const float* __restrict__ inp,
                              const float* __restrict__ normal,
                              float* __restrict__ out, float* __restrict__ ws) {
  const int bp = blockIdx.x * 256 + threadIdx.x;   // 0..16383
  const int b = bp >> 10, p = bp & 1023;

  float azi[3];
#pragma unroll
  for (int i = 0; i < 3; ++i) {
    const float* row = inp + (size_t)((b*NC + 6 + i)*NP + p) * NS;
    float s = 0.f;
#pragma unroll
    for (int q = 0; q < 8; ++q) {
      float4 v = ((const float4*)row)[q];
      s += (v.x + v.y) + (v.z + v.w);
    }
    s -= row[0];                  // mean over s=1..31
    azi[i] = s / 31.f;
  }
  float nr[3];
#pragma unroll
  for (int i = 0; i < 3; ++i) nr[i] = normal[(size_t)(b*NP + p)*3 + i];
  float nn = sqrtf(nr[0]*nr[0] + nr[1]*nr[1] + nr[2]*nr[2]) + 1e-8f;
  nr[0] /= nn; nr[1] /= nn; nr[2] /= nn;
  float au[3] = {azi[0], azi[1], azi[2]};
  float an = sqrtf(au[0]*au[0] + au[1]*au[1] + au[2]*au[2]) + 1e-8f;
  au[0] /= an; au[1] /= an; au[2] /= an;
  float d = au[0]*nr[0] + au[1]*nr[1] + au[2]*nr[2];
  float xax[3] = {au[0] - d*nr[0], au[1] - d*nr[1], au[2] - d*nr[2]};
  float xn = sqrtf(xax[0]*xax[0] + xax[1]*xax[1] + xax[2]*xax[2]) + 1e-8f;
  xax[0] /= xn; xax[1] /= xn; xax[2] /= xn;
  float yax[3] = {nr[1]*xax[2] - nr[2]*xax[1],
                  nr[2]*xax[0] - nr[0]*xax[2],
                  nr[0]*xax[1] - nr[1]*xax[0]};
#pragma unroll
  for (int i = 0; i < 3; ++i)
    out[(size_t)(b*131 + i)*NP + p] = au[i];      // azi_u -> out channels 0..2

  float* w = ws + (size_t)bp * 12;                // R rows (xax,yax,n) + R*azi_u
  w[0]=xax[0]; w[1]=xax[1]; w[2]=xax[2];
  w[3]=yax[0]; w[4]=yax[1]; w[5]=yax[2];
  w[6]=nr[0];  w[7]=nr[1];  w[8]=nr[2];
  w[9]  = xax[0]*au[0] + xax[1]*au[1] + xax[2]*au[2];
  w[10] = yax[0]*au[0] + yax[1]*au[1] + yax[2]*au[2];
  w[11] = nr[0]*au[0]  + nr[1]*au[1]  + nr[2]*au[2];
}

// ---------------- kernel 2: fused MLP + pool ----------------
// 512 threads = 8 waves; wave wv owns output rows 16*wv .. 16*wv+15.
// Per tile (4 points = 128 cols), x in LDS col-major [col=(lp,s)][k], swizzled:
//   k 0..63 feats (ch 12..75); 64..66 align(rel); 67..69 align(o_n); 70..72 dir_dif
//   k 73..95 zero / stale-h1 (annihilated by zero w1 fragments)
// Next tile's global loads are register-staged during current tile's compute.
__global__ __launch_bounds__(512, 2)
void mlp_kernel(const float* __restrict__ inp, const float* __restrict__ w1g,
                const float* __restrict__ b1g, const float* __restrict__ w2g,
                const float* __restrict__ b2g, const float* __restrict__ ws,
                float* __restrict__ out) {
  __shared__ short xh[128 * HSTR];   // 34.8 KB union: x tile, then h1 tile
  const int tid = threadIdx.x;
  const int lane = tid & 63;
  const int wv = tid >> 6;          // wave 0..7 -> output-row stripe 16*wv
  const int l15 = lane & 15;
  const int l4 = lane >> 4;         // 0..3

  const int tile0 = blockIdx.x * TPB;

  // fill-phase thread mapping (feats)
  const int s4 = tid & 7;           // s quad: s = 4*s4..4*s4+3
  const int flp = (tid >> 3) & 3;   // point within tile
  const int chq = tid >> 5;         // channel quad 0..15 -> k = 4*chq
  const int colb = flp*32 + 4*s4;

  // ----- per-wave weight fragments in registers (one 16-row stripe) -----
  bf16x8 w1f[3];
#pragma unroll
  for (int ks = 0; ks < 3; ++ks) {
    bf16x8 a;
#pragma unroll
    for (int j = 0; j < 8; ++j) {
      int row = 16*wv + l15;
      int kk = 32*ks + 8*l4 + j;
      float v = 0.f;
      if (kk < 73) {
        int c = (kk < 64) ? (kk + 3) : ((kk < 67) ? (kk - 64) : kk);
        v = w1g[row*73 + c];
      }
      a[j] = f2bf(v);
    }
    w1f[ks] = a;
  }
  bf16x8 w2f[4];
#pragma unroll
  for (int ks = 0; ks < 4; ++ks) {
    bf16x8 a;
#pragma unroll
    for (int j = 0; j < 8; ++j) {
      int row = 16*wv + l15;
      int kk = 32*ks + 8*l4 + j;
      a[j] = f2bf(w2g[row*128 + kk]);
    }
    w2f[ks] = a;
  }
  float bias1[4], bias2[4];
#pragma unroll
  for (int r = 0; r < 4; ++r) {
    int row = 16*wv + 4*l4 + r;
    bias1[r] = b1g[row];
    bias2[r] = b2g[row];
  }

  // zero pad region k in [73,96) once (tile-0 guard)
  for (int i = tid; i < 128*23; i += 512) {
    int col = i / 23;
    int k = 73 + (i - col*23);
    xh[swz(col, k)] = 0;
  }

  // ----- register stage for tile t+1 (issue-early / write-late) -----
  float4 sf0, sf1, sf2, sf3;    // feats: 4 channels x 4 s
  float sro[9];                 // rel/on/od (tid<128 only)

  auto stage = [&](int it2) {
    const int tile = tile0 + it2;
    const int b = tile >> 8;
    const int pbase = (tile & 255) * 4;
    const float* base = inp + ((size_t)((b*NC + 12 + 4*chq)*NP) + pbase + flp)*NS + 4*s4;
    sf0 = *(const float4*)(base + 0*(size_t)NP*NS);
    sf1 = *(const float4*)(base + 1*(size_t)NP*NS);
    sf2 = *(const float4*)(base + 2*(size_t)NP*NS);
    sf3 = *(const float4*)(base + 3*(size_t)NP*NS);
    if (tid < 128) {
      const int lp = tid >> 5, s = tid & 31;
      const int p = pbase + lp;
#pragma unroll
      for (int i = 0; i < 3; ++i) {
        sro[i]   = inp[(size_t)((b*NC + 6 + i)*NP + p)*NS + s];
        sro[3+i] = inp[(size_t)((b*NC + 3 + i)*NP + p)*NS + s];
        sro[6+i] = inp[(size_t)((b*NC + 9 + i)*NP + p)*NS + s];
      }
    }
  };
  stage(0);

  for (int it = 0; it < TPB; ++it) {
    const int tile = tile0 + it;
    const int b = tile >> 8;
    const int pbase = (tile & 255) * 4;

    if (it > 0) __syncthreads();   // prior tile's L2 fragment reads complete

    // ----- write staged tile to LDS -----
    {
      const float* f0 = (const float*)&sf0;
      const float* f1 = (const float*)&sf1;
      const float* f2 = (const float*)&sf2;
      const float* f3 = (const float*)&sf3;
#pragma unroll
      for (int j = 0; j < 4; ++j) {
        bf16x4 pk;
        pk[0] = f2bf(f0[j]); pk[1] = f2bf(f1[j]);
        pk[2] = f2bf(f2[j]); pk[3] = f2bf(f3[j]);
        *(bf16x4*)&xh[swz(colb + j, 4*chq)] = pk;
      }
    }
    if (tid < 128) {
      const int col = tid;
      const int lp = col >> 5;
      const int p = pbase + lp;
      const float* Rp = ws + (size_t)(b*NP + p)*12;
      float R[12];
#pragma unroll
      for (int i = 0; i < 12; ++i) R[i] = Rp[i];
      float xv[9];
#pragma unroll
      for (int r = 0; r < 3; ++r) {
        xv[r]   = R[3*r]*sro[0] + R[3*r+1]*sro[1] + R[3*r+2]*sro[2];
        xv[3+r] = R[3*r]*sro[3] + R[3*r+1]*sro[4] + R[3*r+2]*sro[5];
        xv[6+r] = R[9+r] - (R[3*r]*sro[6] + R[3*r+1]*sro[7] + R[3*r+2]*sro[8]);
      }
#pragma unroll
      for (int q = 0; q < 4; ++q) {
        bf16x2 pk2; pk2[0] = f2bf(xv[2*q]); pk2[1] = f2bf(xv[2*q+1]);
        *(bf16x2*)&xh[swz(col, 64 + 2*q)] = pk2;
      }
      xh[swz(col, 72)] = f2bf(xv[8]);
    }

    if (it + 1 < TPB) stage(it + 1);   // issue next tile's loads early
    __syncthreads();

    // ----- layer 1: h1 = relu(w1 @ x + b1), K=96 (padded) -----
    f32x4 acc1[8];
#pragma unroll
    for (int nf = 0; nf < 8; ++nf) acc1[nf] = f32x4{0.f,0.f,0.f,0.f};
#pragma unroll
    for (int ks = 0; ks < 3; ++ks) {
      bf16x8 bv[8];
#pragma unroll
      for (int nf = 0; nf < 8; ++nf)
        bv[nf] = *(const bf16x8*)&xh[swz(16*nf + l15, 32*ks + 8*l4)];
#pragma unroll
      for (int nf = 0; nf < 8; ++nf)
        acc1[nf] = __builtin_amdgcn_mfma_f32_16x16x32_bf16(
            w1f[ks], bv[nf], acc1[nf], 0, 0, 0);
    }
    __syncthreads();   // all L1 reads done before h1 overwrites xh

    // store h1 col-major [col][k=row] for layer-2 B fragments
#pragma unroll
    for (int nf = 0; nf < 8; ++nf) {
      const int col = 16*nf + l15;
      const int row0 = 16*wv + 4*l4;
      bf16x4 pk;
#pragma unroll
      for (int r = 0; r < 4; ++r)
        pk[r] = f2bf(fmaxf(acc1[nf][r] + bias1[r], 0.f));
      *(bf16x4*)&xh[swz(col, row0)] = pk;
    }
    __syncthreads();

    // ----- layer 2: h2 = relu(w2 @ h1 + b2), K=128 -----
    f32x4 acc2[8];
#pragma unroll
    for (int nf = 0; nf < 8; ++nf) acc2[nf] = f32x4{0.f,0.f,0.f,0.f};
#pragma unroll
    for (int ks = 0; ks < 4; ++ks) {
      bf16x8 bv[8];
#pragma unroll
      for (int nf = 0; nf < 8; ++nf)
        bv[nf] = *(const bf16x8*)&xh[swz(16*nf + l15, 32*ks + 8*l4)];
#pragma unroll
      for (int nf = 0; nf < 8; ++nf)
        acc2[nf] = __builtin_amdgcn_mfma_f32_16x16x32_bf16(
            w2f[ks], bv[nf], acc2[nf], 0, 0, 0);
    }

    // ----- relu + max-pool over s (DPP butterfly, no LDS) + store -----
#pragma unroll
    for (int r = 0; r < 4; ++r)
#pragma unroll
      for (int lp = 0; lp < 4; ++lp) {
        float v = fmaxf(fmaxf(acc2[2*lp][r], acc2[2*lp+1][r]) + bias2[r], 0.f);
        v = dpp_max16(v);
        if (l15 == lp) {
          const int row = 16*wv + 4*l4 + r;
          out[(size_t)(b*131 + 3 + row)*NP + pbase + lp] = v;
        }
      }
  }
}

extern "C" void kernel_launch(void* const* d_in, const int* in_sizes, int n_in,
                              void* d_out, int out_size, void* d_ws, size_t ws_size,
                              hipStream_t stream) {
  const float* inp    = (const float*)d_in[0];
  const float* normal = (const float*)d_in[1];
  const float* w1     = (const float*)d_in[2];
  const float* b1     = (const float*)d_in[3];
  const float* w2     = (const float*)d_in[4];
  const float* b2     = (const float*)d_in[5];
  float* out = (float*)d_out;
  float* ws  = (float*)d_ws;    // needs 16384*12*4 = 786,432 B

  frames_kernel<<<dim3((NB*NP)/256), dim3(256), 0, stream>>>(inp, normal, out, ws);
  mlp_kernel<<<dim3(NB*NP/4/TPB), dim3(512), 0, stream>>>(inp, w1, b1, w2, b2, ws, out);
}